// Round 22
// baseline (546.891 us; speedup 1.0000x reference)
//
#include <hip/hip_runtime.h>
#include <stdint.h>

namespace {

constexpr int Tn = 512;
constexpr int Sn = 256;
constexpr float EPS = 1e-12f;

typedef _Float16 f16x8 __attribute__((ext_vector_type(8)));
typedef float    f32x4 __attribute__((ext_vector_type(4)));

// Barrier that drains ONLY lgkmcnt (LDS), never vmcnt (T4 pattern).
__device__ __forceinline__ void wg_barrier_lds() {
    asm volatile("s_waitcnt lgkmcnt(0)" ::: "memory");
    __builtin_amdgcn_s_barrier();
}

__launch_bounds__(128, 1)
__global__ void hmm_kernel(const float* __restrict__ emission,  // [B,T,S]
                           const float* __restrict__ weight,    // [S,S]
                           const float* __restrict__ init,      // [S]
                           float* __restrict__ out)             // [B,T,S]
{
    const int tid  = threadIdx.x;      // 0..127
    const int wv   = tid >> 6;         // wave 0..1: owns cols 128wv..128wv+127
    const int lane = tid & 63;
    const int g    = lane >> 4;        // k-lane-group 0..3
    const int jj   = lane & 15;
    const int b    = blockIdx.x;       // batch row

    // carried columns: chains s=g and s=g+4 of this wave
    const int c1 = 128 * wv + 16 * g + jj;
    const int c2 = c1 + 64;

    __shared__ __align__(16) _Float16 wf16[2][Sn];   // dbuf w~ image (f16)
    __shared__ __align__(16) float    s_m[Sn];
    __shared__ __align__(16) float    s_z[Sn];

    // ---- prologue 1: transition softmax row stats (thread owns 2 rows) ----
    #pragma unroll
    for (int h = 0; h < 2; ++h) {
        const int row = tid + 128 * h;
        const float* wr = weight + (size_t)row * Sn;
        float m = -3.402823466e38f;
        #pragma unroll 4
        for (int i = 0; i < Sn; i += 4) {
            float4 v = *reinterpret_cast<const float4*>(wr + i);
            m = fmaxf(m, fmaxf(fmaxf(v.x, v.y), fmaxf(v.z, v.w)));
        }
        float z0 = 0.f, z1 = 0.f, z2 = 0.f, z3 = 0.f;
        #pragma unroll 4
        for (int i = 0; i < Sn; i += 4) {
            float4 v = *reinterpret_cast<const float4*>(wr + i);
            z0 += expf(v.x - m); z1 += expf(v.y - m);
            z2 += expf(v.z - m); z3 += expf(v.w - m);
        }
        s_m[row] = m;
        s_z[row] = 1.f / ((z0 + z1) + (z2 + z3));
    }
    __syncthreads();

    // ---- prologue 2: persistent B fragments, 8 col-sets per wave (f16) ----
    // k-convention (same as A): chunk ck, group g, elem i <-> k = ck*32+g*8+i.
    // bf[s][ck] covers column 128*wv + 16*s + jj.  256 VGPRs, pinned live.
    f16x8 bf[8][8];
    #pragma unroll
    for (int s = 0; s < 8; ++s) {
        const int col = 128 * wv + 16 * s + jj;
        #pragma unroll
        for (int ck = 0; ck < 8; ++ck) {
            #pragma unroll
            for (int i = 0; i < 8; ++i) {
                const int k = ck * 32 + g * 8 + i;
                bf[s][ck][i] =
                    (_Float16)(expf(weight[(size_t)k * Sn + col] - s_m[k]) * s_z[k]);
            }
        }
    }
    // all-ones B operand: D = sum_k A[m,k] -> l1 in reg0 of EVERY lane
    const f16x8 ones8 = {(_Float16)1.f, (_Float16)1.f, (_Float16)1.f, (_Float16)1.f,
                         (_Float16)1.f, (_Float16)1.f, (_Float16)1.f, (_Float16)1.f};

    // ---- prologue 3: initial state softmax -> w~_0 image, e_1 ----
    const float* em1 = emission + (size_t)b * Tn * Sn + c1;
    const float* em2 = emission + (size_t)b * Tn * Sn + c2;
    float*       op1 = out      + (size_t)b * Tn * Sn + c1;
    float*       op2 = out      + (size_t)b * Tn * Sn + c2;
    {
        float i0 = init[lane], i1 = init[lane + 64],
              i2 = init[lane + 128], i3 = init[lane + 192];
        float mx = fmaxf(fmaxf(i0, i1), fmaxf(i2, i3));
        #pragma unroll
        for (int o = 32; o >= 1; o >>= 1) mx = fmaxf(mx, __shfl_xor(mx, o));
        float zz = expf(i0 - mx) + expf(i1 - mx) + expf(i2 - mx) + expf(i3 - mx);
        #pragma unroll
        for (int o = 32; o >= 1; o >>= 1) zz += __shfl_xor(zz, o);
        float u1 = expf(init[c1] - mx) / zz;
        float u2 = expf(init[c2] - mx) / zz;
        wf16[0][c1] = (_Float16)(u1 * em1[0]);
        wf16[0][c2] = (_Float16)(u2 * em2[0]);
    }
    float enext1 = em1[Sn];        // e_1[c1]
    float enext2 = em2[Sn];        // e_1[c2]
    __syncthreads();

#define MFMA(A, B, D) __builtin_amdgcn_mfma_f32_16x16x32_f16((A), (B), (D), 0, 0, 0)

    #pragma unroll 1
    for (int t = 0; t < Tn; ++t) {
        const int p = t & 1;

        // (1) batch-load all 8 A fragments (w~ image, row-broadcast)
        f16x8 af[8];
        #pragma unroll
        for (int ck = 0; ck < 8; ++ck)
            af[ck] = *reinterpret_cast<const f16x8*>(&wf16[p][ck * 32 + g * 8]);
        __builtin_amdgcn_sched_barrier(0);

        // (2) 9 MFMA chains: 8 col-sets (128 cols) + ones (l1)
        f32x4 d0 = {0,0,0,0}, d1 = {0,0,0,0}, d2 = {0,0,0,0}, d3 = {0,0,0,0};
        f32x4 d4 = {0,0,0,0}, d5 = {0,0,0,0}, d6 = {0,0,0,0}, d7 = {0,0,0,0};
        f32x4 dS = {0,0,0,0};
        #pragma unroll
        for (int ck = 0; ck < 8; ++ck) {
            d0 = MFMA(af[ck], bf[0][ck], d0);
            d1 = MFMA(af[ck], bf[1][ck], d1);
            d2 = MFMA(af[ck], bf[2][ck], d2);
            d3 = MFMA(af[ck], bf[3][ck], d3);
            d4 = MFMA(af[ck], bf[4][ck], d4);
            d5 = MFMA(af[ck], bf[5][ck], d5);
            d6 = MFMA(af[ck], bf[6][ck], d6);
            d7 = MFMA(af[ck], bf[7][ck], d7);
            dS = MFMA(af[ck], ones8,    dS);
        }

        // row-broadcast A => reg0 of chain s = y[128wv+16s+jj] in every lane.
        // carried cols: chain g (c1) and chain g+4 (c2).
        float y1 = (g == 0) ? d0[0] : (g == 1) ? d1[0] : (g == 2) ? d2[0] : d3[0];
        float y2 = (g == 0) ? d4[0] : (g == 1) ? d5[0] : (g == 2) ? d6[0] : d7[0];
        float l1 = fmaxf(dS[0], EPS);

        // exact power-of-2 rescale from THIS step's l1
        float sigma = __uint_as_float(0x7f000000u -
                        (__float_as_uint(l1) & 0x7f800000u));

        // Bayes update + image writes (critical tail)
        float wn1 = (y1 * sigma) * enext1;
        float wn2 = (y2 * sigma) * enext2;
        wf16[p ^ 1][c1] = (_Float16)wn1;
        wf16[p ^ 1][c2] = (_Float16)wn2;

        // output stores — off the lgkm path, vmcnt untouched
        float inv = 1.f / l1;
        op1[(size_t)t * Sn] = y1 * inv;
        op2[(size_t)t * Sn] = y2 * inv;

        // prefetch e_{t+2}
        const int tp = (t + 2 < Tn) ? (t + 2) : (Tn - 1);
        enext1 = em1[(size_t)tp * Sn];
        enext2 = em2[(size_t)tp * Sn];

        wg_barrier_lds();     // single lgkm-only barrier per step (2 waves)
    }

#undef MFMA
}

} // namespace

extern "C" void kernel_launch(void* const* d_in, const int* in_sizes, int n_in,
                              void* d_out, int out_size, void* d_ws, size_t ws_size,
                              hipStream_t stream) {
    const float* emission = (const float*)d_in[0];
    const float* weight   = (const float*)d_in[1];
    const float* init     = (const float*)d_in[2];
    float* outp = (float*)d_out;
    const int Bn = in_sizes[0] / (Tn * Sn);   // 128 for the reference shapes

    hipLaunchKernelGGL(hmm_kernel, dim3(Bn), dim3(128), 0, stream,
                       emission, weight, init, outp);
}

// Round 23
// 308.280 us; speedup vs baseline: 1.7740x; 1.7740x over previous
//
#include <hip/hip_runtime.h>
#include <stdint.h>

namespace {

constexpr int Tn = 512;
constexpr int Sn = 256;
constexpr float EPS = 1e-12f;

typedef _Float16 f16x8 __attribute__((ext_vector_type(8)));
typedef float    f32x4 __attribute__((ext_vector_type(4)));

// Barrier that drains ONLY lgkmcnt (LDS), never vmcnt (T4 pattern).
__device__ __forceinline__ void wg_barrier_lds() {
    asm volatile("s_waitcnt lgkmcnt(0)" ::: "memory");
    __builtin_amdgcn_s_barrier();
}

__launch_bounds__(256, 1)
__global__ void hmm_kernel(const float* __restrict__ emission,  // [B,T,S]
                           const float* __restrict__ weight,    // [S,S]
                           const float* __restrict__ init,      // [S]
                           float* __restrict__ out)             // [B,T,S]
{
    const int tid  = threadIdx.x;      // 0..255 == carried column
    const int wv   = tid >> 6;         // wave 0..3: owns cols 64wv .. 64wv+63
    const int lane = tid & 63;
    const int g    = lane >> 4;        // k-lane-group 0..3 (also my col-set)
    const int jj   = lane & 15;
    const int b    = blockIdx.x;       // batch row

    __shared__ __align__(16) _Float16 wf16[2][Sn];   // dbuf w~ image (f16)
    __shared__ __align__(16) float    s_m[Sn];
    __shared__ __align__(16) float    s_z[Sn];

    // ---- prologue 1: transition softmax row stats (thread j owns row j) ----
    {
        const float* wr = weight + (size_t)tid * Sn;
        float m = -3.402823466e38f;
        #pragma unroll 4
        for (int i = 0; i < Sn; i += 4) {
            float4 v = *reinterpret_cast<const float4*>(wr + i);
            m = fmaxf(m, fmaxf(fmaxf(v.x, v.y), fmaxf(v.z, v.w)));
        }
        float z0 = 0.f, z1 = 0.f, z2 = 0.f, z3 = 0.f;
        #pragma unroll 4
        for (int i = 0; i < Sn; i += 4) {
            float4 v = *reinterpret_cast<const float4*>(wr + i);
            z0 += expf(v.x - m); z1 += expf(v.y - m);
            z2 += expf(v.z - m); z3 += expf(v.w - m);
        }
        s_m[tid] = m;
        s_z[tid] = 1.f / ((z0 + z1) + (z2 + z3));
        __syncthreads();
    }

    // ---- prologue 2: persistent B fragments, 4 col-sets per wave (f16) ----
    // Shared k-convention with A: chunk ck, group g, elem i <-> k = ck*32+g*8+i.
    // bf[s][ck] covers column 64*wv + 16*s + jj.
    f16x8 bf[4][8];
    #pragma unroll
    for (int s = 0; s < 4; ++s) {
        const int col = 64 * wv + 16 * s + jj;
        #pragma unroll
        for (int ck = 0; ck < 8; ++ck) {
            #pragma unroll
            for (int i = 0; i < 8; ++i) {
                const int k = ck * 32 + g * 8 + i;
                bf[s][ck][i] =
                    (_Float16)(expf(weight[(size_t)k * Sn + col] - s_m[k]) * s_z[k]);
            }
        }
    }
    // all-ones B operand: D = sum_k A[m,k] -> l1 in reg0 of EVERY lane
    const f16x8 ones8 = {(_Float16)1.f, (_Float16)1.f, (_Float16)1.f, (_Float16)1.f,
                         (_Float16)1.f, (_Float16)1.f, (_Float16)1.f, (_Float16)1.f};

    // ---- prologue 3: initial state softmax -> w~_0 image, e_1 ----
    const float* em = emission + (size_t)b * Tn * Sn + tid;
    float*       op = out      + (size_t)b * Tn * Sn + tid;
    {
        float i0 = init[lane], i1 = init[lane + 64],
              i2 = init[lane + 128], i3 = init[lane + 192];
        float mx = fmaxf(fmaxf(i0, i1), fmaxf(i2, i3));
        #pragma unroll
        for (int o = 32; o >= 1; o >>= 1) mx = fmaxf(mx, __shfl_xor(mx, o));
        float zz = expf(i0 - mx) + expf(i1 - mx) + expf(i2 - mx) + expf(i3 - mx);
        #pragma unroll
        for (int o = 32; o >= 1; o >>= 1) zz += __shfl_xor(zz, o);
        float u  = expf(init[tid] - mx) / zz;
        wf16[0][tid] = (_Float16)(u * em[0]);
    }
    float enext   = em[Sn];    // e_1[tid]
    float y_prev  = 0.f;       // y_{t-1} for the lagged store
    float l1_prev = 1.0f;      // l1_{t-1}; 1.0 => sigma=1 at t=0 (no rescale)
    __syncthreads();

#define MFMA(A, B, D) __builtin_amdgcn_mfma_f32_16x16x32_f16((A), (B), (D), 0, 0, 0)

    #pragma unroll 1
    for (int t = 0; t < Tn; ++t) {
        const int p = t & 1;

        // (1) issue all 8 A-fragment reads (w~ image, row-broadcast)
        f16x8 af[8];
        #pragma unroll
        for (int ck = 0; ck < 8; ++ck)
            af[ck] = *reinterpret_cast<const f16x8*>(&wf16[p][ck * 32 + g * 8]);
        __builtin_amdgcn_sched_barrier(0);

        // (2) latency window — VALU work with NO dependence on af, executed
        // while the ds_reads are in flight:
        //   e_{t+2} prefetch, sigma from l1_{t-1} (exact pow2; scale-invariant
        //   recursion => outputs bit-identical), se = sigma*e, lagged store.
        const int tp = (t + 2 < Tn) ? (t + 2) : (Tn - 1);
        const float e2 = em[(size_t)tp * Sn];
        uint32_t ebits = __float_as_uint(l1_prev) & 0x7f800000u;
        float sig = __uint_as_float(0x7f000000u - ebits);
        float se  = sig * enext;
        if (t) op[(size_t)(t - 1) * Sn] = y_prev * (1.f / l1_prev);
        __builtin_amdgcn_sched_barrier(0);

        // (3) 5 MFMA chains (4 col-sets + ones)
        f32x4 d0 = {0,0,0,0}, d1 = {0,0,0,0}, d2 = {0,0,0,0}, d3 = {0,0,0,0};
        f32x4 dS = {0,0,0,0};
        #pragma unroll
        for (int ck = 0; ck < 8; ++ck) {
            d0 = MFMA(af[ck], bf[0][ck], d0);
            d1 = MFMA(af[ck], bf[1][ck], d1);
            d2 = MFMA(af[ck], bf[2][ck], d2);
            d3 = MFMA(af[ck], bf[3][ck], d3);
            dS = MFMA(af[ck], ones8,    dS);
        }

        // (4) minimal critical tail: select y -> one mul -> cvt -> ds_write
        float y  = (g == 0) ? d0[0] : (g == 1) ? d1[0] : (g == 2) ? d2[0] : d3[0];
        float wn = y * se;                       // w~_{t+1}[tid] (lagged sigma)
        wf16[p ^ 1][tid] = (_Float16)wn;

        y_prev  = y;
        l1_prev = fmaxf(dS[0], EPS);             // off critical path (sinks)
        enext   = e2;

        wg_barrier_lds();     // single lgkm-only barrier per step
    }

    // epilogue: out_{T-1}
    op[(size_t)(Tn - 1) * Sn] = y_prev * (1.f / l1_prev);

#undef MFMA
}

} // namespace

extern "C" void kernel_launch(void* const* d_in, const int* in_sizes, int n_in,
                              void* d_out, int out_size, void* d_ws, size_t ws_size,
                              hipStream_t stream) {
    const float* emission = (const float*)d_in[0];
    const float* weight   = (const float*)d_in[1];
    const float* init     = (const float*)d_in[2];
    float* outp = (float*)d_out;
    const int Bn = in_sizes[0] / (Tn * Sn);   // 128 for the reference shapes

    hipLaunchKernelGGL(hmm_kernel, dim3(Bn), dim3(256), 0, stream,
                       emission, weight, init, outp);
}